// Round 11
// baseline (2272.110 us; speedup 1.0000x reference)
//
#include <hip/hip_runtime.h>
#include <hip/hip_bf16.h>

// Problem constants
#define B_    128
#define T_    512
#define IN_   128
#define H_    1024
#define OUT_  64
#define KTOT  1152          // IN_ + H_
#define GH    64            // hidden groups (16 units, 64 gate cols each)
#define GB    4             // batch groups (32 rows each)
// Blocked Hall layout: [t][cg(256 col-groups of 4)][rh(8 row-halves of 16)][16][4]
// element (b,c) -> (c>>2)*512 + (b>>4)*64 + (b&15)*4 + (c&3) ushorts.
// t-slab stride = 131072 ushorts (256KB). Each producer wave's 16x4 tile is
// 128B contiguous & 128B aligned -> line-clean single-writer publish.
#define HSLAB 131072

typedef short bf16x8 __attribute__((ext_vector_type(8)));
typedef short s16x4  __attribute__((ext_vector_type(4)));
typedef float f32x4  __attribute__((ext_vector_type(4)));

#define MFMA(a,b,c) __builtin_amdgcn_mfma_f32_16x16x32_bf16((a),(b),(c),0,0,0)

__device__ __forceinline__ unsigned short f2bf(float x) {
    unsigned int xi = __float_as_uint(x);
    unsigned int r  = (xi + 0x7fffu + ((xi >> 16) & 1u)) >> 16;
    return (unsigned short)r;
}

// ---------------------------------------------------------------------------
// Pack combined recurrent weights: Wp[c][k] bf16, c = gh*64 + unit_local*4 + gate
// gate 0,1,2 = f,i,z (kernel_fiz col gate*H + j); gate 3 = r (kernel_r col j)
// ---------------------------------------------------------------------------
__global__ void pack_weights(const float* __restrict__ kfiz, const float* __restrict__ kr,
                             const float* __restrict__ bfiz, const float* __restrict__ br,
                             unsigned short* __restrict__ Wp, float* __restrict__ biasp)
{
    const int c    = blockIdx.x;            // 0..4095
    const int gh   = c >> 6, nl = c & 63;
    const int j    = gh * 16 + (nl >> 2);
    const int gate = nl & 3;
    for (int k = threadIdx.x; k < KTOT; k += 256) {
        float v = (gate < 3) ? kfiz[(size_t)k * 3072 + gate * 1024 + j]
                             : kr[(size_t)k * 1024 + j];
        Wp[(size_t)c * KTOT + k] = f2bf(v);
    }
    if (threadIdx.x == 0)
        biasp[c] = (gate < 3) ? bfiz[gate * 1024 + j] : br[j];
}

// u (B,T,IN) fp32 -> Ubf (T,B,IN) bf16
__global__ void pack_u(const float* __restrict__ u, unsigned short* __restrict__ Ubf)
{
    size_t i = (size_t)blockIdx.x * 256 + threadIdx.x;   // < 8388608
    int t = (int)(i >> 14);
    int rem = (int)(i & 16383);
    int b = rem >> 7, k = rem & 127;
    Ubf[i] = f2bf(u[((size_t)b << 16) + ((size_t)t << 7) + k]);
}

// W_out (H,OUT) fp32 -> Wob[o][k] bf16
__global__ void pack_wout(const float* __restrict__ wo, unsigned short* __restrict__ Wob)
{
    const int o = blockIdx.x;               // 0..63
    for (int k = threadIdx.x; k < H_; k += 256)
        Wob[(size_t)o * H_ + k] = f2bf(wo[(size_t)k * OUT_ + o]);
}

// ---------------------------------------------------------------------------
// Persistent recurrent scan — round-4 proven protocol + LINE-CLEAN DISTRIBUTED
// publish (deletes hT LDS, B2b, and the wave0 funnel).
//  * Producer tail: each wave transposes its owned 16x4 hn tile in-register
//    (2x shfl_xor butterfly among same-gate lanes, proven r5/r8), stores it as
//    16 lanes x 8B = one 128B contiguous, 128B-aligned run (single writer per
//    64B line -> no partial-line RMW, the defect that sank round 3). Per-wave
//    vmcnt(0) drain runs in PARALLEL across the 8 waves; raw s_barrier; tid0
//    sets the per-WG flag (flag = "visible", keeps consumer loads PLAIN).
//  * Consumer: wave0-only TIGHT 64-flag poll (r10 lesson: poll body weight
//    delays discovery; r6 lesson: never add pollers), B1, then plain cached
//    loads — now two 8B loads per K-chunk (col-groups are 4 wide).
//  * Everything else byte-identical to the 1900us round-4 kernel.
// ---------------------------------------------------------------------------
__global__ void __launch_bounds__(512, 2)
lstm_scan(const float* __restrict__ x0,
          const unsigned short* __restrict__ Wp,
          const float* __restrict__ biasp,
          const unsigned short* __restrict__ Ubf,
          unsigned short* __restrict__ Hall,
          int* __restrict__ Flag)
{
    __shared__ float part[4 * 8 * 320];       // [nj][mi*4+tl][col*20 + row] 40 KB

    const int tid  = threadIdx.x;
    const int bid  = blockIdx.x;
    const int gb   = (bid & 7) >> 1;                 // XCD-pair -> one gb group
    const int gh   = ((bid & 1) << 5) | (bid >> 3);  // 0..63, unique per gb
    const int wave = tid >> 6;
    const int lane = tid & 63;
    const int mi   = wave & 1;
    const int nj   = wave >> 1;               // K-slice AND owner-tile index, 0..3
    const int quad = lane >> 4;
    const int l15  = lane & 15;
    const int g    = l15 & 3;                 // gate id of this lane's column

    // Weights: tile tl cols gh*64+tl*16+l15, K-slice nj chunks kk (9 x 32).
    f32x4 wregf[36];
    #pragma unroll
    for (int tl = 0; tl < 4; ++tl)
        #pragma unroll
        for (int kk = 0; kk < 9; ++kk)
            wregf[tl * 9 + kk] = *reinterpret_cast<const f32x4*>(
                Wp + (size_t)(gh * 64 + tl * 16 + l15) * KTOT + nj * 288 + kk * 32 + quad * 8);
    #pragma unroll
    for (int i = 0; i < 36; ++i)
        asm volatile("" : "+v"(wregf[i]));    // pin: no remat, keep in VGPRs

    const float bias = biasp[gh * 64 + nj * 16 + l15];   // owner-role bias

    const int rowBase = gb * 32 + mi * 16;
    const int j       = gh * 16 + nj * 4 + (l15 >> 2);   // owner-role unit col

    // c-state (fp32, replicated across the 4 gate lanes of each unit)
    float cst[4];
    #pragma unroll
    for (int r = 0; r < 4; ++r)
        cst[r] = x0[(size_t)(rowBase + quad * 4 + r) * 2048 + 1024 + j];

    // h0 -> Hall[0] (blocked layout; one-time scattered 2B stores are fine)
    {
        int m = tid >> 4, u16 = tid & 15;     // rows 0..31, cols 0..15 of patch
        int b = gb * 32 + m, c = gh * 16 + u16;
        unsigned short hv = f2bf(x0[(size_t)b * 2048 + c]);
        size_t adr = (size_t)(c >> 2) * 512 + (size_t)(b >> 4) * 64
                   + (b & 15) * 4 + (c & 3);
        __hip_atomic_store(&Hall[adr], hv,
                           __ATOMIC_RELAXED, __HIP_MEMORY_SCOPE_AGENT);
    }
    __syncthreads();                           // one-time drain (off steady path)
    if (tid == 0)
        __hip_atomic_store(&Flag[(size_t)gb * 64 + gh], 1,
                           __ATOMIC_RELAXED, __HIP_MEMORY_SCOPE_AGENT);

    const int aRow = rowBase + l15;            // A-frag row (batch index)
    const unsigned short* aU = Ubf + (size_t)aRow * IN_ + quad * 8;
    // Consumer base: row part (b>>4)*64 + (b&15)*4, quad picks 2 col-groups.
    const unsigned short* aH = Hall + (size_t)(gb * 2 + mi) * 64 + l15 * 4
                             + (size_t)quad * 1024;      // quad*2 col-groups
    const ptrdiff_t hCg0 = (ptrdiff_t)(nj * 72 - 32) * 512;  // kk=0 cg offset

    const int kk0 = (nj == 0) ? 4 : 0;         // post-poll chunk start

    // Producer publish address (per-lane, g==0 lanes store): wave tile
    // cg = gh*4+nj, rh = gb*2+mi, row-in-half = quad*4 + (l15>>2).
    const size_t pubAdr = (size_t)(gh * 4 + nj) * 512 + (size_t)(gb * 2 + mi) * 64
                        + (size_t)(quad * 4 + (l15 >> 2)) * 4;

    for (int t = 0; t < T_; ++t) {
        f32x4 acc[4] = {{0.f,0.f,0.f,0.f},{0.f,0.f,0.f,0.f},
                        {0.f,0.f,0.f,0.f},{0.f,0.f,0.f,0.f}};

        // ---- pre-poll u-part (nj==0 waves own K-chunks 0..3 = u) ----
        if (nj == 0) {
            const unsigned short* au = aU + (size_t)t * (B_ * IN_);
            #pragma unroll
            for (int kk = 0; kk < 4; ++kk) {
                bf16x8 av = *reinterpret_cast<const bf16x8*>(au + kk * 32);
                #pragma unroll
                for (int tl = 0; tl < 4; ++tl)
                    acc[tl] = MFMA(av, __builtin_bit_cast(bf16x8, wregf[tl * 9 + kk]), acc[tl]);
            }
        }

        // ---- wait for h[t]: wave0-only TIGHT 64-flag poll (r4 verbatim) ----
        if (wave == 0) {
            const int* fp = Flag + ((size_t)t * GB + gb) * 64 + lane;
            int v = __hip_atomic_load(fp, __ATOMIC_RELAXED, __HIP_MEMORY_SCOPE_AGENT);
            for (int gd = 0; gd < (1 << 20) && !__all(v != 0); ++gd)
                v = __hip_atomic_load(fp, __ATOMIC_RELAXED, __HIP_MEMORY_SCOPE_AGENT);
        }
        __syncthreads();                       // B1

        // ---- h-part: this wave's K-slice (two 8B plain loads per chunk) ----
        const unsigned short* ahT = aH + (size_t)t * HSLAB + hCg0;
        bf16x8 a[9];
        #pragma unroll
        for (int kk = 0; kk < 9; ++kk)
            if (kk >= kk0) {
                union { s16x4 h[2]; bf16x8 v; } uu;
                uu.h[0] = *reinterpret_cast<const s16x4*>(ahT + (ptrdiff_t)kk * 4096);
                uu.h[1] = *reinterpret_cast<const s16x4*>(ahT + (ptrdiff_t)kk * 4096 + 512);
                a[kk] = uu.v;
            }
        #pragma unroll
        for (int kk = 0; kk < 9; ++kk)
            if (kk >= kk0) {
                #pragma unroll
                for (int tl = 0; tl < 4; ++tl)
                    acc[tl] = MFMA(a[kk], __builtin_bit_cast(bf16x8, wregf[tl * 9 + kk]), acc[tl]);
            }

        // ---- write partials to LDS: part[nj][mi*4+tl][col l15][rows quad*4..] ----
        #pragma unroll
        for (int tl = 0; tl < 4; ++tl)
            *reinterpret_cast<f32x4*>(
                &part[(nj * 8 + mi * 4 + tl) * 320 + l15 * 20 + quad * 4]) = acc[tl];
        __syncthreads();                       // B2a

        // ---- owner reduce (this wave owns tile tl == nj for row-half mi) ----
        f32x4 s = {bias, bias, bias, bias};
        {
            const int rbase = (mi * 4 + nj) * 320 + l15 * 20 + quad * 4;
            #pragma unroll
            for (int njj = 0; njj < 4; ++njj)
                s += *reinterpret_cast<const f32x4*>(&part[njj * 2560 + rbase]);
        }

        // ---- epilogue: activations, cross-gate exchange, state update ----
        unsigned int hx = 0, hy = 0;           // 4 packed bf16 hn (rows r=0..3)
        #pragma unroll
        for (int r = 0; r < 4; ++r) {
            float pre = s[r];
            float sg  = 1.0f / (1.0f + __expf((g == 3) ? -2.0f * pre : -pre));
            float act = (g == 3) ? 2.0f * sg - 1.0f : sg;
            float x1 = __shfl_xor(act, 1);
            float x2 = __shfl_xor(act, 2);
            float x3 = __shfl_xor(x1, 2);
            float fv = (g == 0) ? act : (g == 1) ? x1 : (g == 2) ? x2 : x3;
            int gi = g ^ 1;
            float iv = (gi == 0) ? act : (gi == 1) ? x1 : (gi == 2) ? x2 : x3;
            int gz = g ^ 2;
            float zv = (gz == 0) ? act : (gz == 1) ? x1 : (gz == 2) ? x2 : x3;
            int gr = g ^ 3;
            float rv = (gr == 0) ? act : (gr == 1) ? x1 : (gr == 2) ? x2 : x3;

            float cn = fv * cst[r] + iv * rv;
            cst[r] = cn;
            float th = 2.0f / (1.0f + __expf(-2.0f * cn)) - 1.0f;
            float hn = zv * th;
            unsigned int hb = f2bf(hn);
            if (r == 0)      hx  = hb;
            else if (r == 1) hx |= hb << 16;
            else if (r == 2) hy  = hb;
            else             hy |= hb << 16;
        }

        // ---- in-register 4x4 transpose among same-gate lanes (bits 2..3) ----
        // lane u = l15>>2 ends holding row quad*4+u's 4 cols packed [c0..c3].
        unsigned int px = __shfl_xor((int)hx, 4), py = __shfl_xor((int)hy, 4);
        unsigned int ax, ay;
        if ((lane & 4) == 0) { ax = (hx & 0xFFFFu) | (px << 16);
                               ay = (hy & 0xFFFFu) | (py << 16); }
        else                 { ax = (px >> 16) | (hx & 0xFFFF0000u);
                               ay = (py >> 16) | (hy & 0xFFFF0000u); }
        unsigned int qx = __shfl_xor((int)ax, 8), qy = __shfl_xor((int)ay, 8);
        unsigned int bx, by;
        if ((lane & 8) == 0) { bx = ax; by = qx; }
        else                 { bx = qy; by = ay; }

        // ---- distributed LINE-CLEAN publish: wave's 128B contiguous tile ----
        if (g == 0) {
            unsigned long long val = ((unsigned long long)by << 32) | bx;
            __hip_atomic_store(
                (unsigned long long*)&Hall[(size_t)(t + 1) * HSLAB + pubAdr], val,
                __ATOMIC_RELAXED, __HIP_MEMORY_SCOPE_AGENT);
        }
        // per-wave drain (parallel across 8 waves), raw barrier, then flag.
        asm volatile("s_waitcnt vmcnt(0)" ::: "memory");
        asm volatile("s_barrier" ::: "memory");
        if (tid == 0)
            __hip_atomic_store(&Flag[((size_t)(t + 1) * GB + gb) * 64 + gh], 1,
                               __ATOMIC_RELAXED, __HIP_MEMORY_SCOPE_AGENT);
    }
}

// ---------------------------------------------------------------------------
// y[b][t][o] = Hall[t+1][.] @ Wob[o][:] + bout[o]   (cg-blocked Hall)
// ---------------------------------------------------------------------------
__global__ void __launch_bounds__(256, 2)
out_gemm(const unsigned short* __restrict__ Hall,
         const unsigned short* __restrict__ Wob,
         const float* __restrict__ bout,
         float* __restrict__ y)
{
    const int tid  = threadIdx.x, wave = tid >> 6, lane = tid & 63;
    const int quad = lane >> 4, l15 = lane & 15;
    const int R    = blockIdx.x * 64 + wave * 16;      // flat row t*128+b

    f32x4 acc[4];
    #pragma unroll
    for (int nt = 0; nt < 4; ++nt) {
        float bb = bout[nt * 16 + l15];
        acc[nt] = {bb, bb, bb, bb};
    }
    const int fr = R + l15;                    // flat row; same t across the wave
    const int br = fr & 127;
    const unsigned short* ap = Hall + ((size_t)(fr >> 7) + 1) * HSLAB
                             + (size_t)(br >> 4) * 64 + (br & 15) * 4
                             + (size_t)quad * 1024;
    #pragma unroll 4
    for (int kk = 0; kk < 32; ++kk) {          // chunk kk = col-groups kk*8+quad*2
        union { s16x4 h[2]; bf16x8 v; } uu;
        uu.h[0] = *reinterpret_cast<const s16x4*>(ap + (size_t)kk * 4096);
        uu.h[1] = *reinterpret_cast<const s16x4*>(ap + (size_t)kk * 4096 + 512);
        bf16x8 av = uu.v;
        #pragma unroll
        for (int nt = 0; nt < 4; ++nt) {
            bf16x8 bv = *reinterpret_cast<const bf16x8*>(
                Wob + (size_t)(nt * 16 + l15) * H_ + kk * 32 + quad * 8);
            acc[nt] = MFMA(av, bv, acc[nt]);
        }
    }
    #pragma unroll
    for (int nt = 0; nt < 4; ++nt)
        #pragma unroll
        for (int r = 0; r < 4; ++r) {
            int row = R + quad * 4 + r;
            int b = row & 127, t = row >> 7;
            y[((size_t)b << 15) + ((size_t)t << 6) + nt * 16 + l15] = acc[nt][r];
        }
}

// ---------------------------------------------------------------------------
extern "C" void kernel_launch(void* const* d_in, const int* in_sizes, int n_in,
                              void* d_out, int out_size, void* d_ws, size_t ws_size,
                              hipStream_t stream)
{
    const float* u    = (const float*)d_in[0];
    const float* x0   = (const float*)d_in[1];
    const float* kfiz = (const float*)d_in[2];
    const float* bfiz = (const float*)d_in[3];
    const float* kr   = (const float*)d_in[4];
    const float* br   = (const float*)d_in[5];
    const float* wo   = (const float*)d_in[6];
    const float* bo   = (const float*)d_in[7];
    float* y = (float*)d_out;

    char* ws = (char*)d_ws;
    size_t off = 0;
    unsigned short* Wp    = (unsigned short*)(ws + off); off += (size_t)4096 * KTOT * 2;        // 9,437,184
    float*          biasp = (float*)(ws + off);          off += (size_t)4096 * 4;               // 16,384
    unsigned short* Wob   = (unsigned short*)(ws + off); off += (size_t)OUT_ * H_ * 2;          // 131,072
    unsigned short* Ubf   = (unsigned short*)(ws + off); off += (size_t)T_ * B_ * IN_ * 2;      // 16,777,216
    unsigned short* Hall  = (unsigned short*)(ws + off); off += (size_t)(T_ + 1) * B_ * H_ * 2; // 134,479,872
    int*            Flag  = (int*)(ws + off);            off += (size_t)(T_ + 1) * GB * 64 * 4; // 525,312
    if (off > ws_size) return;   // workspace too small: deterministic visible failure

    hipMemsetAsync(Flag, 0, (size_t)(T_ + 1) * GB * 64 * 4, stream);
    hipLaunchKernelGGL(pack_weights, dim3(4096),  dim3(256), 0, stream, kfiz, kr, bfiz, br, Wp, biasp);
    hipLaunchKernelGGL(pack_u,       dim3(32768), dim3(256), 0, stream, u, Ubf);
    hipLaunchKernelGGL(pack_wout,    dim3(64),    dim3(256), 0, stream, wo, Wob);

    void* args[] = { (void*)&x0, (void*)&Wp, (void*)&biasp, (void*)&Ubf, (void*)&Hall, (void*)&Flag };
    hipLaunchCooperativeKernel((void*)lstm_scan, dim3(GB * GH), dim3(512), args, 0, stream);

    hipLaunchKernelGGL(out_gemm, dim3((T_ * B_) / 64), dim3(256), 0, stream, Hall, Wob, bo, y);
}